// Round 1
// baseline (748.580 us; speedup 1.0000x reference)
//
#include <hip/hip_runtime.h>
#include <cstdint>
#include <cstddef>

#define NB 2048     // batch
#define NT 512      // topics
#define ND 64       // embed dim
#define NA 64       // att dim
#define NR 50       // reviews per sample
#define TC 128      // t-chunk
#define NCH (NT / TC)

// ---------------------------------------------------------------------------
// colsum[d] = sum_t topic_w[t][d]
__global__ __launch_bounds__(256) void colsum_kernel(const float* __restrict__ tw,
                                                     float* __restrict__ colsum) {
    __shared__ float part[4][ND];
    int d = threadIdx.x & 63, p = threadIdx.x >> 6;
    float s = 0.f;
    for (int t = p; t < NT; t += 4) s += tw[t * ND + d];
    part[p][d] = s;
    __syncthreads();
    if (threadIdx.x < ND)
        colsum[d] = part[0][d] + part[1][d] + part[2][d] + part[3][d];
}

// ---------------------------------------------------------------------------
// One block per (branch, batch element). 256 threads = 4 waves.
__global__ __launch_bounds__(256) void branch_kernel(
    const int* __restrict__ user, const int* __restrict__ item,
    const float* __restrict__ user_r_topic, const float* __restrict__ item_r_topic,
    const float* __restrict__ user_embed_w, const float* __restrict__ item_embed_w,
    const float* __restrict__ user_att_w, const float* __restrict__ item_att_w,
    const float* __restrict__ topic_w,
    const float* __restrict__ fc_u_w, const float* __restrict__ fc_u_b,
    const float* __restrict__ fc_ru_w, const float* __restrict__ fc_ru_b,
    const float* __restrict__ fc_i_w, const float* __restrict__ fc_i_b,
    const float* __restrict__ fc_ri_w, const float* __restrict__ fc_ri_b,
    const float* __restrict__ h_u_w, const float* __restrict__ h_u_b,
    const float* __restrict__ h_i_w, const float* __restrict__ h_i_b,
    const float* __restrict__ colsum,
    float* __restrict__ u_vec, float* __restrict__ i_vec)
{
    const int bb = blockIdx.x;
    const int branch = bb >> 11;          // 0 = user, 1 = item
    const int b = bb & (NB - 1);

    const int*   ids     = branch ? item           : user;
    const float* r_topic = branch ? item_r_topic   : user_r_topic;
    const float* emb_w   = branch ? item_embed_w   : user_embed_w;
    const float* att_w   = branch ? item_att_w     : user_att_w;
    const float* fc_a_w  = branch ? fc_i_w         : fc_u_w;
    const float* fc_a_b  = branch ? fc_i_b         : fc_u_b;
    const float* fc_r_w  = branch ? fc_ri_w        : fc_ru_w;
    const float* fc_r_b  = branch ? fc_ri_b        : fc_ru_b;
    const float* h_w     = branch ? h_i_w          : h_u_w;
    const float* h_b     = branch ? h_i_b          : h_u_b;
    float*       out_vec = branch ? i_vec          : u_vec;

    // LDS: 64*132*4 = 33792 B  +  50*128*4 = 25600 B  + small  ~= 60 KB
    __shared__ float lds_tw[ND][TC + 4];   // transposed topic chunk [d][t]
    __shared__ float lds_r[NR][TC];        // r_topic chunk; reused as review[NR][ND]
    __shared__ float lds_att[ND];
    __shared__ float lds_logit[NR];

    const int tid = threadIdx.x, wave = tid >> 6, lane = tid & 63;
    const int id = ids[b];

    if (tid < ND) lds_att[tid] = att_w[(size_t)id * ND + tid];

    float acc[13];
#pragma unroll
    for (int k = 0; k < 13; ++k) acc[k] = 0.f;

    const float* rbase = r_topic + (size_t)b * NR * NT;

    for (int c = 0; c < NCH; ++c) {
        // stage topic chunk, transposed (coalesced global read)
        for (int i = tid; i < TC * ND; i += 256) {
            int t = i >> 6, d = i & 63;
            lds_tw[d][t] = topic_w[(size_t)(c * TC + t) * ND + d];
        }
        // stage r_topic chunk as float4 (rows contiguous)
        for (int i = tid; i < NR * (TC / 4); i += 256) {
            int r = i >> 5;           // TC/4 == 32
            int t4 = i & 31;
            float4 v = *reinterpret_cast<const float4*>(
                rbase + (size_t)r * NT + c * TC + t4 * 4);
            *reinterpret_cast<float4*>(&lds_r[r][t4 * 4]) = v;
        }
        __syncthreads();

#pragma unroll 4
        for (int t4 = 0; t4 < TC / 4; ++t4) {
            float4 tw = *reinterpret_cast<const float4*>(&lds_tw[lane][t4 * 4]);
#pragma unroll
            for (int k = 0; k < 13; ++k) {
                int r = wave + 4 * k;
                if (r < NR) {
                    float4 rv = *reinterpret_cast<const float4*>(&lds_r[r][t4 * 4]);
                    acc[k] = fmaf(rv.x, tw.x, acc[k]);
                    acc[k] = fmaf(rv.y, tw.y, acc[k]);
                    acc[k] = fmaf(rv.z, tw.z, acc[k]);
                    acc[k] = fmaf(rv.w, tw.w, acc[k]);
                }
            }
        }
        __syncthreads();
    }

    // review -> LDS (reuse lds_r storage)
    float (*lds_review)[ND] = reinterpret_cast<float(*)[ND]>(lds_r);
#pragma unroll
    for (int k = 0; k < 13; ++k) {
        int r = wave + 4 * k;
        if (r < NR) lds_review[r][lane] = acc[k];
    }
    __syncthreads();

    // attention projection of att vector (each wave computes its own copy); lane = a
    float attproj = fc_a_b[lane];
    for (int d = 0; d < ND; ++d)
        attproj = fmaf(lds_att[d], fc_a_w[d * NA + lane], attproj);

    // s = relu(attproj + review @ fc_r_w + fc_r_b); logit = s @ h_w + h_b
    float sacc[13];
    const float frb = fc_r_b[lane];
#pragma unroll
    for (int k = 0; k < 13; ++k) sacc[k] = attproj + frb;
    for (int d = 0; d < ND; ++d) {
        float fw = fc_r_w[d * NA + lane];
#pragma unroll
        for (int k = 0; k < 13; ++k) {
            int r = wave + 4 * k;
            if (r < NR) sacc[k] = fmaf(lds_review[r][d], fw, sacc[k]);
        }
    }
    const float hwv = h_w[lane];
    const float hb = h_b[0];
#pragma unroll
    for (int k = 0; k < 13; ++k) {
        int r = wave + 4 * k;
        if (r < NR) {
            float v = fmaxf(sacc[k], 0.f) * hwv;
#pragma unroll
            for (int off = 32; off; off >>= 1) v += __shfl_xor(v, off);
            if (lane == 0) lds_logit[r] = v + hb;
        }
    }
    __syncthreads();

    // softmax over NR + attention pooling + colsum scale + emb add (wave 0)
    if (wave == 0) {
        float m = -1e30f;
        for (int r = 0; r < NR; ++r) m = fmaxf(m, lds_logit[r]);
        float sum = 0.f;
        for (int r = 0; r < NR; ++r) sum += __expf(lds_logit[r] - m);
        float inv = 1.f / sum;
        float feat = 0.f;
        for (int r = 0; r < NR; ++r)
            feat = fmaf(__expf(lds_logit[r] - m), lds_review[r][lane], feat);
        feat *= inv;
        float outv = feat * colsum[lane] + emb_w[(size_t)id * ND + lane];
        out_vec[(size_t)b * ND + lane] = outv;
    }
}

// ---------------------------------------------------------------------------
// pred[b] = relu( [u_vec ; i_vec] @ fc_pre_w + fc_pre_b )
__global__ __launch_bounds__(64) void final_kernel(
    const float* __restrict__ u_vec, const float* __restrict__ i_vec,
    const float* __restrict__ fc_pre_w, const float* __restrict__ fc_pre_b,
    float* __restrict__ out)
{
    int b = blockIdx.x, lane = threadIdx.x;
    float v = u_vec[(size_t)b * ND + lane] * fc_pre_w[lane]
            + i_vec[(size_t)b * ND + lane] * fc_pre_w[ND + lane];
#pragma unroll
    for (int off = 32; off; off >>= 1) v += __shfl_xor(v, off);
    if (lane == 0) out[b] = fmaxf(v + fc_pre_b[0], 0.f);
}

// ---------------------------------------------------------------------------
extern "C" void kernel_launch(void* const* d_in, const int* in_sizes, int n_in,
                              void* d_out, int out_size, void* d_ws, size_t ws_size,
                              hipStream_t stream) {
    (void)in_sizes; (void)n_in; (void)out_size; (void)ws_size;

    const int*   user         = (const int*)d_in[0];
    const int*   item         = (const int*)d_in[1];
    const float* user_r_topic = (const float*)d_in[2];
    const float* item_r_topic = (const float*)d_in[3];
    const float* user_embed_w = (const float*)d_in[4];
    const float* item_embed_w = (const float*)d_in[5];
    const float* user_att_w   = (const float*)d_in[6];
    const float* item_att_w   = (const float*)d_in[7];
    const float* topic_w      = (const float*)d_in[8];
    const float* fc_u_w       = (const float*)d_in[9];
    const float* fc_u_b       = (const float*)d_in[10];
    const float* fc_ru_w      = (const float*)d_in[11];
    const float* fc_ru_b      = (const float*)d_in[12];
    const float* fc_i_w       = (const float*)d_in[13];
    const float* fc_i_b       = (const float*)d_in[14];
    const float* fc_ri_w      = (const float*)d_in[15];
    const float* fc_ri_b      = (const float*)d_in[16];
    const float* h_u_w        = (const float*)d_in[17];
    const float* h_u_b        = (const float*)d_in[18];
    const float* h_i_w        = (const float*)d_in[19];
    const float* h_i_b        = (const float*)d_in[20];
    const float* fc_pre_w     = (const float*)d_in[21];
    const float* fc_pre_b     = (const float*)d_in[22];

    float* ws     = (float*)d_ws;
    float* colsum = ws;                    // 64 floats
    float* u_vec  = ws + 64;               // NB*ND
    float* i_vec  = u_vec + NB * ND;       // NB*ND

    colsum_kernel<<<1, 256, 0, stream>>>(topic_w, colsum);

    branch_kernel<<<2 * NB, 256, 0, stream>>>(
        user, item, user_r_topic, item_r_topic,
        user_embed_w, item_embed_w, user_att_w, item_att_w, topic_w,
        fc_u_w, fc_u_b, fc_ru_w, fc_ru_b,
        fc_i_w, fc_i_b, fc_ri_w, fc_ri_b,
        h_u_w, h_u_b, h_i_w, h_i_b,
        colsum, u_vec, i_vec);

    final_kernel<<<NB, 64, 0, stream>>>(u_vec, i_vec, fc_pre_w, fc_pre_b,
                                        (float*)d_out);
}

// Round 2
// 275.547 us; speedup vs baseline: 2.7167x; 2.7167x over previous
//
#include <hip/hip_runtime.h>
#include <cstdint>
#include <cstddef>

#define NB 2048     // batch
#define NT 512      // topics
#define ND 64       // embed dim
#define NA 64       // att dim
#define NR 50       // reviews per sample
#define NKK (NT / 32)   // 16 k-steps of 32

typedef __attribute__((ext_vector_type(8))) short bf16x8;
typedef __attribute__((ext_vector_type(4))) float f32x4;

__device__ inline unsigned short f2bf_rne(float x) {
    unsigned int u = __float_as_uint(x);
    u += 0x7fffu + ((u >> 16) & 1u);
    return (unsigned short)(u >> 16);
}
__device__ inline float bf2f(unsigned short h) {
    return __uint_as_float(((unsigned int)h) << 16);
}

// ---------------------------------------------------------------------------
// Pre-pack topic_w [512][64] into MFMA B-fragment order, split hi/lo bf16.
// Element (kk, n, lane, j) holds B[k][col] with k = kk*32 + (lane>>4)*8 + j,
// col = n*16 + (lane&15). One thread per element; 32768 elements.
__global__ __launch_bounds__(256) void prep_kernel(
    const float* __restrict__ tw,
    unsigned short* __restrict__ bhi, unsigned short* __restrict__ blo)
{
    int i = blockIdx.x * 256 + threadIdx.x;          // 128 blocks * 256 = 32768
    int j  = i & 7;
    int l  = (i >> 3) & 63;
    int n  = (i >> 9) & 3;
    int kk = i >> 11;
    int t = kk * 32 + ((l >> 4) << 3) + j;
    int d = n * 16 + (l & 15);
    float x = tw[t * ND + d];
    unsigned short hi = f2bf_rne(x);
    bhi[i] = hi;
    blo[i] = f2bf_rne(x - bf2f(hi));
}

// ---------------------------------------------------------------------------
// colsum[d] = sum_t topic_w[t][d]
__global__ __launch_bounds__(256) void colsum_kernel(const float* __restrict__ tw,
                                                     float* __restrict__ colsum) {
    __shared__ float part[4][ND];
    int d = threadIdx.x & 63, p = threadIdx.x >> 6;
    float s = 0.f;
    for (int t = p; t < NT; t += 4) s += tw[t * ND + d];
    part[p][d] = s;
    __syncthreads();
    if (threadIdx.x < ND)
        colsum[d] = part[0][d] + part[1][d] + part[2][d] + part[3][d];
}

// ---------------------------------------------------------------------------
// One block per (branch, batch element). 4 waves; wave w owns review rows
// 16w..16w+15. Main GEMM: no LDS, A from global in frag layout, B pre-packed.
__global__ __launch_bounds__(256) void branch_kernel(
    const int* __restrict__ user, const int* __restrict__ item,
    const float* __restrict__ user_r_topic, const float* __restrict__ item_r_topic,
    const float* __restrict__ user_embed_w, const float* __restrict__ item_embed_w,
    const float* __restrict__ user_att_w, const float* __restrict__ item_att_w,
    const unsigned short* __restrict__ bhi, const unsigned short* __restrict__ blo,
    const float* __restrict__ fc_u_w, const float* __restrict__ fc_u_b,
    const float* __restrict__ fc_ru_w, const float* __restrict__ fc_ru_b,
    const float* __restrict__ fc_i_w, const float* __restrict__ fc_i_b,
    const float* __restrict__ fc_ri_w, const float* __restrict__ fc_ri_b,
    const float* __restrict__ h_u_w, const float* __restrict__ h_u_b,
    const float* __restrict__ h_i_w, const float* __restrict__ h_i_b,
    const float* __restrict__ colsum,
    float* __restrict__ u_vec, float* __restrict__ i_vec)
{
    const int bb = blockIdx.x;
    const int branch = bb >> 11;          // 0 = user, 1 = item
    const int b = bb & (NB - 1);

    const int*   ids     = branch ? item           : user;
    const float* r_topic = branch ? item_r_topic   : user_r_topic;
    const float* emb_w   = branch ? item_embed_w   : user_embed_w;
    const float* att_w   = branch ? item_att_w     : user_att_w;
    const float* fc_a_w  = branch ? fc_i_w         : fc_u_w;
    const float* fc_a_b  = branch ? fc_i_b         : fc_u_b;
    const float* fc_r_w  = branch ? fc_ri_w        : fc_ru_w;
    const float* fc_r_b  = branch ? fc_ri_b        : fc_ru_b;
    const float* h_w     = branch ? h_i_w          : h_u_w;
    const float* h_b     = branch ? h_i_b          : h_u_b;
    float*       out_vec = branch ? i_vec          : u_vec;

    __shared__ float lds_review[64][66];   // rows 50..63 are pad
    __shared__ float lds_att[ND];
    __shared__ float lds_logit[NR];

    const int tid = threadIdx.x, wave = tid >> 6, lane = tid & 63;
    const int g = lane >> 4;               // k-group within frag
    const int id = ids[b];

    if (tid < ND) lds_att[tid] = att_w[(size_t)id * ND + tid];

    // ---- bf16x3 MFMA GEMM: review[64][64] = A[64][512] @ B[512][64] ----
    int row = wave * 16 + (lane & 15);
    if (row > NR - 1) row = NR - 1;        // clamp pad rows (values unused)
    const float* arow = r_topic + (size_t)b * NR * NT + (size_t)row * NT + g * 8;

    f32x4 acc[4];
#pragma unroll
    for (int n = 0; n < 4; ++n) acc[n] = (f32x4){0.f, 0.f, 0.f, 0.f};

#pragma unroll 2
    for (int kk = 0; kk < NKK; ++kk) {
        float4 v0 = *reinterpret_cast<const float4*>(arow + kk * 32);
        float4 v1 = *reinterpret_cast<const float4*>(arow + kk * 32 + 4);
        float va[8] = {v0.x, v0.y, v0.z, v0.w, v1.x, v1.y, v1.z, v1.w};
        bf16x8 ah, al;
#pragma unroll
        for (int j = 0; j < 8; ++j) {
            unsigned short h = f2bf_rne(va[j]);
            ah[j] = (short)h;
            al[j] = (short)f2bf_rne(va[j] - bf2f(h));
        }
#pragma unroll
        for (int n = 0; n < 4; ++n) {
            const size_t off = (size_t)((kk * 4 + n) * 64 + lane) * 8;
            bf16x8 bh = *reinterpret_cast<const bf16x8*>(bhi + off);
            bf16x8 bl = *reinterpret_cast<const bf16x8*>(blo + off);
            acc[n] = __builtin_amdgcn_mfma_f32_16x16x32_bf16(ah, bh, acc[n], 0, 0, 0);
            acc[n] = __builtin_amdgcn_mfma_f32_16x16x32_bf16(ah, bl, acc[n], 0, 0, 0);
            acc[n] = __builtin_amdgcn_mfma_f32_16x16x32_bf16(al, bh, acc[n], 0, 0, 0);
        }
    }

    // C layout: lane holds rows (lane>>4)*4 + r4 (within wave tile), col n*16 + (lane&15)
#pragma unroll
    for (int n = 0; n < 4; ++n)
#pragma unroll
        for (int r4 = 0; r4 < 4; ++r4)
            lds_review[wave * 16 + g * 4 + r4][n * 16 + (lane & 15)] = acc[n][r4];
    __syncthreads();

    // ---- epilogue (identical math to round-1, which matched exactly) ----
    // attention projection of att vector (each wave computes its own copy); lane = a
    float attproj = fc_a_b[lane];
    for (int d = 0; d < ND; ++d)
        attproj = fmaf(lds_att[d], fc_a_w[d * NA + lane], attproj);

    // s = relu(attproj + review @ fc_r_w + fc_r_b); logit = s @ h_w + h_b
    float sacc[13];
    const float frb = fc_r_b[lane];
#pragma unroll
    for (int k = 0; k < 13; ++k) sacc[k] = attproj + frb;
    for (int d = 0; d < ND; ++d) {
        float fw = fc_r_w[d * NA + lane];
#pragma unroll
        for (int k = 0; k < 13; ++k) {
            int r = wave + 4 * k;
            if (r < NR) sacc[k] = fmaf(lds_review[r][d], fw, sacc[k]);
        }
    }
    const float hwv = h_w[lane];
    const float hb = h_b[0];
#pragma unroll
    for (int k = 0; k < 13; ++k) {
        int r = wave + 4 * k;
        if (r < NR) {
            float v = fmaxf(sacc[k], 0.f) * hwv;
#pragma unroll
            for (int off = 32; off; off >>= 1) v += __shfl_xor(v, off);
            if (lane == 0) lds_logit[r] = v + hb;
        }
    }
    __syncthreads();

    // softmax over NR + attention pooling + colsum scale + emb add (wave 0)
    if (wave == 0) {
        float m = -1e30f;
        for (int r = 0; r < NR; ++r) m = fmaxf(m, lds_logit[r]);
        float sum = 0.f;
        for (int r = 0; r < NR; ++r) sum += __expf(lds_logit[r] - m);
        float inv = 1.f / sum;
        float feat = 0.f;
        for (int r = 0; r < NR; ++r)
            feat = fmaf(__expf(lds_logit[r] - m), lds_review[r][lane], feat);
        feat *= inv;
        float outv = feat * colsum[lane] + emb_w[(size_t)id * ND + lane];
        out_vec[(size_t)b * ND + lane] = outv;
    }
}

// ---------------------------------------------------------------------------
// pred[b] = relu( [u_vec ; i_vec] @ fc_pre_w + fc_pre_b )
__global__ __launch_bounds__(64) void final_kernel(
    const float* __restrict__ u_vec, const float* __restrict__ i_vec,
    const float* __restrict__ fc_pre_w, const float* __restrict__ fc_pre_b,
    float* __restrict__ out)
{
    int b = blockIdx.x, lane = threadIdx.x;
    float v = u_vec[(size_t)b * ND + lane] * fc_pre_w[lane]
            + i_vec[(size_t)b * ND + lane] * fc_pre_w[ND + lane];
#pragma unroll
    for (int off = 32; off; off >>= 1) v += __shfl_xor(v, off);
    if (lane == 0) out[b] = fmaxf(v + fc_pre_b[0], 0.f);
}

// ---------------------------------------------------------------------------
extern "C" void kernel_launch(void* const* d_in, const int* in_sizes, int n_in,
                              void* d_out, int out_size, void* d_ws, size_t ws_size,
                              hipStream_t stream) {
    (void)in_sizes; (void)n_in; (void)out_size; (void)ws_size;

    const int*   user         = (const int*)d_in[0];
    const int*   item         = (const int*)d_in[1];
    const float* user_r_topic = (const float*)d_in[2];
    const float* item_r_topic = (const float*)d_in[3];
    const float* user_embed_w = (const float*)d_in[4];
    const float* item_embed_w = (const float*)d_in[5];
    const float* user_att_w   = (const float*)d_in[6];
    const float* item_att_w   = (const float*)d_in[7];
    const float* topic_w      = (const float*)d_in[8];
    const float* fc_u_w       = (const float*)d_in[9];
    const float* fc_u_b       = (const float*)d_in[10];
    const float* fc_ru_w      = (const float*)d_in[11];
    const float* fc_ru_b      = (const float*)d_in[12];
    const float* fc_i_w       = (const float*)d_in[13];
    const float* fc_i_b       = (const float*)d_in[14];
    const float* fc_ri_w      = (const float*)d_in[15];
    const float* fc_ri_b      = (const float*)d_in[16];
    const float* h_u_w        = (const float*)d_in[17];
    const float* h_u_b        = (const float*)d_in[18];
    const float* h_i_w        = (const float*)d_in[19];
    const float* h_i_b        = (const float*)d_in[20];
    const float* fc_pre_w     = (const float*)d_in[21];
    const float* fc_pre_b     = (const float*)d_in[22];

    // workspace layout (16B-aligned pieces)
    unsigned short* bhi = (unsigned short*)d_ws;             // 32768 ushort
    unsigned short* blo = bhi + 32768;                       // 32768 ushort
    float* colsum = (float*)(blo + 32768);                   // 64 f32
    float* u_vec  = colsum + 64;                             // NB*ND
    float* i_vec  = u_vec + NB * ND;                         // NB*ND

    prep_kernel<<<128, 256, 0, stream>>>(topic_w, bhi, blo);
    colsum_kernel<<<1, 256, 0, stream>>>(topic_w, colsum);

    branch_kernel<<<2 * NB, 256, 0, stream>>>(
        user, item, user_r_topic, item_r_topic,
        user_embed_w, item_embed_w, user_att_w, item_att_w,
        bhi, blo,
        fc_u_w, fc_u_b, fc_ru_w, fc_ru_b,
        fc_i_w, fc_i_b, fc_ri_w, fc_ri_b,
        h_u_w, h_u_b, h_i_w, h_i_b,
        colsum, u_vec, i_vec);

    final_kernel<<<NB, 64, 0, stream>>>(u_vec, i_vec, fc_pre_w, fc_pre_b,
                                        (float*)d_out);
}

// Round 3
// 241.267 us; speedup vs baseline: 3.1027x; 1.1421x over previous
//
#include <hip/hip_runtime.h>
#include <cstdint>
#include <cstddef>

#define NB 2048     // batch
#define NT 512      // topics
#define ND 64       // embed dim
#define NA 64       // att dim
#define NR 50       // reviews per sample
#define NKK (NT / 32)   // 16 k-steps of 32

typedef __attribute__((ext_vector_type(8))) short bf16x8;
typedef __attribute__((ext_vector_type(4))) float f32x4;

__device__ inline unsigned short f2bf_rne(float x) {
    unsigned int u = __float_as_uint(x);
    u += 0x7fffu + ((u >> 16) & 1u);
    return (unsigned short)(u >> 16);
}

// exact split: hi = truncate(x) to bf16, lo = rne(x - hi)
__device__ inline void cvt8(const float4 v0, const float4 v1,
                            bf16x8& ah, bf16x8& al) {
    float va[8] = {v0.x, v0.y, v0.z, v0.w, v1.x, v1.y, v1.z, v1.w};
#pragma unroll
    for (int j = 0; j < 8; ++j) {
        unsigned int u = __float_as_uint(va[j]);
        ah[j] = (short)(u >> 16);
        float hf = __uint_as_float(u & 0xffff0000u);
        al[j] = (short)f2bf_rne(va[j] - hf);
    }
}

// ---------------------------------------------------------------------------
// Pre-pack topic_w [512][64] into MFMA B-fragment order, split hi/lo bf16.
// Element (kk, n, lane, j) holds B[k][col] with k = kk*32 + (lane>>4)*8 + j,
// col = n*16 + (lane&15).
__global__ __launch_bounds__(256) void prep_kernel(
    const float* __restrict__ tw,
    unsigned short* __restrict__ bhi, unsigned short* __restrict__ blo)
{
    int i = blockIdx.x * 256 + threadIdx.x;          // 128 blocks * 256 = 32768
    int j  = i & 7;
    int l  = (i >> 3) & 63;
    int n  = (i >> 9) & 3;
    int kk = i >> 11;
    int t = kk * 32 + ((l >> 4) << 3) + j;
    int d = n * 16 + (l & 15);
    float x = tw[t * ND + d];
    unsigned int u = __float_as_uint(x);
    unsigned short hi = (unsigned short)(u >> 16);    // truncation split
    bhi[i] = hi;
    blo[i] = f2bf_rne(x - __uint_as_float(u & 0xffff0000u));
}

// ---------------------------------------------------------------------------
// colsum[d] = sum_t topic_w[t][d]
__global__ __launch_bounds__(256) void colsum_kernel(const float* __restrict__ tw,
                                                     float* __restrict__ colsum) {
    __shared__ float part[4][ND];
    int d = threadIdx.x & 63, p = threadIdx.x >> 6;
    float s = 0.f;
    for (int t = p; t < NT; t += 4) s += tw[t * ND + d];
    part[p][d] = s;
    __syncthreads();
    if (threadIdx.x < ND)
        colsum[d] = part[0][d] + part[1][d] + part[2][d] + part[3][d];
}

// ---------------------------------------------------------------------------
// One block per (branch, batch-PAIR). 4 waves; wave w owns review rows
// 16w..16w+15 of BOTH batch elements. B-frags reused for 6 MFMAs each.
__global__ __launch_bounds__(256) void branch_kernel(
    const int* __restrict__ user, const int* __restrict__ item,
    const float* __restrict__ user_r_topic, const float* __restrict__ item_r_topic,
    const float* __restrict__ user_embed_w, const float* __restrict__ item_embed_w,
    const float* __restrict__ user_att_w, const float* __restrict__ item_att_w,
    const unsigned short* __restrict__ bhi, const unsigned short* __restrict__ blo,
    const float* __restrict__ fc_u_w, const float* __restrict__ fc_u_b,
    const float* __restrict__ fc_ru_w, const float* __restrict__ fc_ru_b,
    const float* __restrict__ fc_i_w, const float* __restrict__ fc_i_b,
    const float* __restrict__ fc_ri_w, const float* __restrict__ fc_ri_b,
    const float* __restrict__ h_u_w, const float* __restrict__ h_u_b,
    const float* __restrict__ h_i_w, const float* __restrict__ h_i_b,
    const float* __restrict__ colsum,
    float* __restrict__ u_vec, float* __restrict__ i_vec)
{
    const int bb = blockIdx.x;
    const int branch = bb >> 10;          // 0 = user, 1 = item
    const int pair = bb & 1023;
    const int b0 = pair * 2, b1 = b0 + 1;

    const int*   ids     = branch ? item           : user;
    const float* r_topic = branch ? item_r_topic   : user_r_topic;
    const float* emb_w   = branch ? item_embed_w   : user_embed_w;
    const float* att_w   = branch ? item_att_w     : user_att_w;
    const float* fc_a_w  = branch ? fc_i_w         : fc_u_w;
    const float* fc_a_b  = branch ? fc_i_b         : fc_u_b;
    const float* fc_r_w  = branch ? fc_ri_w        : fc_ru_w;
    const float* fc_r_b  = branch ? fc_ri_b        : fc_ru_b;
    const float* h_w     = branch ? h_i_w          : h_u_w;
    const float* h_b     = branch ? h_i_b          : h_u_b;
    float*       out_vec = branch ? i_vec          : u_vec;

    __shared__ float lds_review[2][NR][66];
    __shared__ float lds_att[2][ND];
    __shared__ float lds_logit[2][NR];

    const int tid = threadIdx.x, wave = tid >> 6, lane = tid & 63;
    const int g = lane >> 4;
    const int id0 = ids[b0], id1 = ids[b1];

    if (tid < 64) lds_att[0][tid] = att_w[(size_t)id0 * ND + tid];
    else if (tid < 128) lds_att[1][tid - 64] = att_w[(size_t)id1 * ND + (tid - 64)];

    // ---- bf16-split MFMA GEMM: review[b][64][64] = A[b][64][512] @ B ----
    int row = wave * 16 + (lane & 15);
    if (row > NR - 1) row = NR - 1;        // clamp pad rows (values unused)
    const float* arow0 = r_topic + (size_t)b0 * NR * NT + (size_t)row * NT + g * 8;
    const float* arow1 = arow0 + (size_t)NR * NT;

    f32x4 acc0[4], acc1[4];
#pragma unroll
    for (int n = 0; n < 4; ++n) {
        acc0[n] = (f32x4){0.f, 0.f, 0.f, 0.f};
        acc1[n] = (f32x4){0.f, 0.f, 0.f, 0.f};
    }

    float4 c00 = *reinterpret_cast<const float4*>(arow0);
    float4 c01 = *reinterpret_cast<const float4*>(arow0 + 4);
    float4 c10 = *reinterpret_cast<const float4*>(arow1);
    float4 c11 = *reinterpret_cast<const float4*>(arow1 + 4);

#pragma unroll 2
    for (int kk = 0; kk < NKK; ++kk) {
        // issue next-iteration A loads before this iteration's compute
        const int kn = (kk + 1 < NKK ? kk + 1 : kk) * 32;
        float4 n00 = *reinterpret_cast<const float4*>(arow0 + kn);
        float4 n01 = *reinterpret_cast<const float4*>(arow0 + kn + 4);
        float4 n10 = *reinterpret_cast<const float4*>(arow1 + kn);
        float4 n11 = *reinterpret_cast<const float4*>(arow1 + kn + 4);

        bf16x8 ah0, al0, ah1, al1;
        cvt8(c00, c01, ah0, al0);
        cvt8(c10, c11, ah1, al1);

#pragma unroll
        for (int n = 0; n < 4; ++n) {
            const size_t off = (size_t)((kk * 4 + n) * 64 + lane) * 8;
            bf16x8 bh = *reinterpret_cast<const bf16x8*>(bhi + off);
            bf16x8 bl = *reinterpret_cast<const bf16x8*>(blo + off);
            acc0[n] = __builtin_amdgcn_mfma_f32_16x16x32_bf16(ah0, bh, acc0[n], 0, 0, 0);
            acc1[n] = __builtin_amdgcn_mfma_f32_16x16x32_bf16(ah1, bh, acc1[n], 0, 0, 0);
            acc0[n] = __builtin_amdgcn_mfma_f32_16x16x32_bf16(ah0, bl, acc0[n], 0, 0, 0);
            acc1[n] = __builtin_amdgcn_mfma_f32_16x16x32_bf16(ah1, bl, acc1[n], 0, 0, 0);
            acc0[n] = __builtin_amdgcn_mfma_f32_16x16x32_bf16(al0, bh, acc0[n], 0, 0, 0);
            acc1[n] = __builtin_amdgcn_mfma_f32_16x16x32_bf16(al1, bh, acc1[n], 0, 0, 0);
        }
        c00 = n00; c01 = n01; c10 = n10; c11 = n11;
    }

    // C layout: lane holds rows g*4 + r4 (within wave tile), col n*16 + (lane&15)
#pragma unroll
    for (int n = 0; n < 4; ++n)
#pragma unroll
        for (int r4 = 0; r4 < 4; ++r4) {
            int r = wave * 16 + g * 4 + r4;
            if (r < NR) {
                lds_review[0][r][n * 16 + (lane & 15)] = acc0[n][r4];
                lds_review[1][r][n * 16 + (lane & 15)] = acc1[n][r4];
            }
        }
    __syncthreads();

    // ---- epilogue: attention MLP for both batch elements ----
    float ap0 = fc_a_b[lane], ap1 = ap0;
    for (int d = 0; d < ND; ++d) {
        float fw = fc_a_w[d * NA + lane];
        ap0 = fmaf(lds_att[0][d], fw, ap0);
        ap1 = fmaf(lds_att[1][d], fw, ap1);
    }

    float sacc0[13], sacc1[13];
    const float frb = fc_r_b[lane];
#pragma unroll
    for (int k = 0; k < 13; ++k) { sacc0[k] = ap0 + frb; sacc1[k] = ap1 + frb; }
    for (int d = 0; d < ND; ++d) {
        float fw = fc_r_w[d * NA + lane];
#pragma unroll
        for (int k = 0; k < 13; ++k) {
            int r = wave + 4 * k;
            if (r < NR) {
                sacc0[k] = fmaf(lds_review[0][r][d], fw, sacc0[k]);
                sacc1[k] = fmaf(lds_review[1][r][d], fw, sacc1[k]);
            }
        }
    }
    const float hwv = h_w[lane];
    const float hb = h_b[0];
#pragma unroll
    for (int k = 0; k < 13; ++k) {
        int r = wave + 4 * k;
        if (r < NR) {
            float v0 = fmaxf(sacc0[k], 0.f) * hwv;
            float v1 = fmaxf(sacc1[k], 0.f) * hwv;
#pragma unroll
            for (int off = 32; off; off >>= 1) {
                v0 += __shfl_xor(v0, off);
                v1 += __shfl_xor(v1, off);
            }
            if (lane == 0) {
                lds_logit[0][r] = v0 + hb;
                lds_logit[1][r] = v1 + hb;
            }
        }
    }
    __syncthreads();

    // softmax + pooling + colsum scale + emb add (wave 0 -> b0, wave 1 -> b1)
    if (wave < 2) {
        const int bi = wave;
        const int b = bi ? b1 : b0;
        const int id = bi ? id1 : id0;
        float m = -1e30f;
        for (int r = 0; r < NR; ++r) m = fmaxf(m, lds_logit[bi][r]);
        float sum = 0.f;
        for (int r = 0; r < NR; ++r) sum += __expf(lds_logit[bi][r] - m);
        float inv = 1.f / sum;
        float feat = 0.f;
        for (int r = 0; r < NR; ++r)
            feat = fmaf(__expf(lds_logit[bi][r] - m), lds_review[bi][r][lane], feat);
        feat *= inv;
        float outv = feat * colsum[lane] + emb_w[(size_t)id * ND + lane];
        out_vec[(size_t)b * ND + lane] = outv;
    }
}

// ---------------------------------------------------------------------------
// pred[b] = relu( [u_vec ; i_vec] @ fc_pre_w + fc_pre_b )
__global__ __launch_bounds__(64) void final_kernel(
    const float* __restrict__ u_vec, const float* __restrict__ i_vec,
    const float* __restrict__ fc_pre_w, const float* __restrict__ fc_pre_b,
    float* __restrict__ out)
{
    int b = blockIdx.x, lane = threadIdx.x;
    float v = u_vec[(size_t)b * ND + lane] * fc_pre_w[lane]
            + i_vec[(size_t)b * ND + lane] * fc_pre_w[ND + lane];
#pragma unroll
    for (int off = 32; off; off >>= 1) v += __shfl_xor(v, off);
    if (lane == 0) out[b] = fmaxf(v + fc_pre_b[0], 0.f);
}

// ---------------------------------------------------------------------------
extern "C" void kernel_launch(void* const* d_in, const int* in_sizes, int n_in,
                              void* d_out, int out_size, void* d_ws, size_t ws_size,
                              hipStream_t stream) {
    (void)in_sizes; (void)n_in; (void)out_size; (void)ws_size;

    const int*   user         = (const int*)d_in[0];
    const int*   item         = (const int*)d_in[1];
    const float* user_r_topic = (const float*)d_in[2];
    const float* item_r_topic = (const float*)d_in[3];
    const float* user_embed_w = (const float*)d_in[4];
    const float* item_embed_w = (const float*)d_in[5];
    const float* user_att_w   = (const float*)d_in[6];
    const float* item_att_w   = (const float*)d_in[7];
    const float* topic_w      = (const float*)d_in[8];
    const float* fc_u_w       = (const float*)d_in[9];
    const float* fc_u_b       = (const float*)d_in[10];
    const float* fc_ru_w      = (const float*)d_in[11];
    const float* fc_ru_b      = (const float*)d_in[12];
    const float* fc_i_w       = (const float*)d_in[13];
    const float* fc_i_b       = (const float*)d_in[14];
    const float* fc_ri_w      = (const float*)d_in[15];
    const float* fc_ri_b      = (const float*)d_in[16];
    const float* h_u_w        = (const float*)d_in[17];
    const float* h_u_b        = (const float*)d_in[18];
    const float* h_i_w        = (const float*)d_in[19];
    const float* h_i_b        = (const float*)d_in[20];
    const float* fc_pre_w     = (const float*)d_in[21];
    const float* fc_pre_b     = (const float*)d_in[22];

    // workspace layout (16B-aligned pieces)
    unsigned short* bhi = (unsigned short*)d_ws;             // 32768 ushort
    unsigned short* blo = bhi + 32768;                       // 32768 ushort
    float* colsum = (float*)(blo + 32768);                   // 64 f32
    float* u_vec  = colsum + 64;                             // NB*ND
    float* i_vec  = u_vec + NB * ND;                         // NB*ND

    prep_kernel<<<128, 256, 0, stream>>>(topic_w, bhi, blo);
    colsum_kernel<<<1, 256, 0, stream>>>(topic_w, colsum);

    branch_kernel<<<2 * (NB / 2), 256, 0, stream>>>(
        user, item, user_r_topic, item_r_topic,
        user_embed_w, item_embed_w, user_att_w, item_att_w,
        bhi, blo,
        fc_u_w, fc_u_b, fc_ru_w, fc_ru_b,
        fc_i_w, fc_i_b, fc_ri_w, fc_ri_b,
        h_u_w, h_u_b, h_i_w, h_i_b,
        colsum, u_vec, i_vec);

    final_kernel<<<NB, 64, 0, stream>>>(u_vec, i_vec, fc_pre_w, fc_pre_b,
                                        (float*)d_out);
}

// Round 4
// 160.370 us; speedup vs baseline: 4.6678x; 1.5044x over previous
//
#include <hip/hip_runtime.h>
#include <cstdint>
#include <cstddef>

#define NB 2048
#define NT 512
#define ND 64
#define NR 50
#define NKK 16
#define REVP 68   // review row stride (floats): 272B = 17*16, 16B-aligned rows

typedef __attribute__((ext_vector_type(8))) short bf16x8;
typedef __attribute__((ext_vector_type(4))) float f32x4;

__device__ inline unsigned short f2bf_rne(float x) {
    unsigned int u = __float_as_uint(x);
    u += 0x7fffu + ((u >> 16) & 1u);
    return (unsigned short)(u >> 16);
}

// split 8 f32 -> hi (truncate) / lo (RNE of remainder), packed as bf16x8
__device__ inline void cvt8_fast(float4 v0, float4 v1, bf16x8& ah, bf16x8& al) {
    float f[8] = {v0.x, v0.y, v0.z, v0.w, v1.x, v1.y, v1.z, v1.w};
    union { unsigned int u[4]; bf16x8 v; } H, L;
#pragma unroll
    for (int p = 0; p < 4; ++p) {
        unsigned int u0 = __float_as_uint(f[2*p]);
        unsigned int u1 = __float_as_uint(f[2*p+1]);
        H.u[p] = (u0 >> 16) | (u1 & 0xffff0000u);
        float r0 = f[2*p]   - __uint_as_float(u0 & 0xffff0000u);
        float r1 = f[2*p+1] - __uint_as_float(u1 & 0xffff0000u);
        unsigned int lp;
        asm("v_cvt_pk_bf16_f32 %0, %1, %2" : "=v"(lp) : "v"(r0), "v"(r1));
        L.u[p] = lp;
    }
    ah = H.v; al = L.v;
}

__device__ inline void gload16(const void* gsrc, void* ldst) {
    __builtin_amdgcn_global_load_lds(
        (const __attribute__((address_space(1))) unsigned int*)gsrc,
        (__attribute__((address_space(3))) unsigned int*)ldst, 16, 0, 0);
}

// ---------------------------------------------------------------------------
// Pack topic_w into main-GEMM B-frag order (hi/lo) and fc weights into
// epilogue B-frag order (K=128: rows 0-63 = fc_r_w, 64-127 = fc_a_w).
__global__ __launch_bounds__(256) void prep_kernel(
    const float* __restrict__ tw,
    const float* __restrict__ fc_u_w, const float* __restrict__ fc_ru_w,
    const float* __restrict__ fc_i_w, const float* __restrict__ fc_ri_w,
    unsigned short* __restrict__ bhi, unsigned short* __restrict__ blo,
    unsigned short* __restrict__ fuhi, unsigned short* __restrict__ fulo,
    unsigned short* __restrict__ fihi, unsigned short* __restrict__ filo)
{
    int i = blockIdx.x * 256 + threadIdx.x;          // 192*256 = 49152
    if (i < 32768) {
        int j  = i & 7;
        int l  = (i >> 3) & 63;
        int n  = (i >> 9) & 3;
        int kk = i >> 11;                            // 0..15
        int t = kk * 32 + ((l >> 4) << 3) + j;
        int d = n * 16 + (l & 15);
        float x = tw[t * ND + d];
        unsigned int u = __float_as_uint(x);
        bhi[i] = (unsigned short)(u >> 16);
        blo[i] = f2bf_rne(x - __uint_as_float(u & 0xffff0000u));
    } else {
        int q = i - 32768;                           // 0..16383
        int br = q >> 13;                            // 0 user, 1 item
        int e = q & 8191;
        int j  = e & 7;
        int l  = (e >> 3) & 63;
        int n  = (e >> 9) & 3;
        int kk = e >> 11;                            // 0..3
        int k = kk * 32 + ((l >> 4) << 3) + j;       // 0..127
        int col = n * 16 + (l & 15);
        const float* W = (k < 64) ? (br ? fc_ri_w : fc_ru_w)
                                  : (br ? fc_i_w  : fc_u_w);
        float x = W[(k & 63) * ND + col];
        unsigned int u = __float_as_uint(x);
        unsigned short hi = (unsigned short)(u >> 16);
        unsigned short lo = f2bf_rne(x - __uint_as_float(u & 0xffff0000u));
        if (br) { fihi[e] = hi; filo[e] = lo; }
        else    { fuhi[e] = hi; fulo[e] = lo; }
    }
}

// ---------------------------------------------------------------------------
__global__ __launch_bounds__(256) void colsum_kernel(const float* __restrict__ tw,
                                                     float* __restrict__ colsum) {
    __shared__ float part[4][ND];
    int d = threadIdx.x & 63, p = threadIdx.x >> 6;
    float s = 0.f;
    for (int t = p; t < NT; t += 4) s += tw[t * ND + d];
    part[p][d] = s;
    __syncthreads();
    if (threadIdx.x < ND)
        colsum[d] = part[0][d] + part[1][d] + part[2][d] + part[3][d];
}

// ---------------------------------------------------------------------------
// One block per (branch, batch element). 4 waves. Double-buffered async
// global_load_lds staging for A (swizzled placement) and B (pre-packed frags).
__global__ __launch_bounds__(256, 4) void branch_kernel(
    const int* __restrict__ user, const int* __restrict__ item,
    const float* __restrict__ user_r_topic, const float* __restrict__ item_r_topic,
    const float* __restrict__ user_embed_w, const float* __restrict__ item_embed_w,
    const float* __restrict__ user_att_w, const float* __restrict__ item_att_w,
    const unsigned short* __restrict__ bhi, const unsigned short* __restrict__ blo,
    const unsigned short* __restrict__ fuhi, const unsigned short* __restrict__ fulo,
    const unsigned short* __restrict__ fihi, const unsigned short* __restrict__ filo,
    const float* __restrict__ fc_u_b, const float* __restrict__ fc_ru_b,
    const float* __restrict__ fc_i_b, const float* __restrict__ fc_ri_b,
    const float* __restrict__ h_u_w, const float* __restrict__ h_u_b,
    const float* __restrict__ h_i_w, const float* __restrict__ h_i_b,
    const float* __restrict__ colsum,
    float* __restrict__ u_vec, float* __restrict__ i_vec)
{
    const int bb = blockIdx.x;
    const int branch = bb >> 11;          // 0 = user, 1 = item
    const int b = bb & (NB - 1);

    const int*   ids     = branch ? item           : user;
    const float* r_topic = branch ? item_r_topic   : user_r_topic;
    const float* emb_w   = branch ? item_embed_w   : user_embed_w;
    const float* att_w   = branch ? item_att_w     : user_att_w;
    const unsigned short* fhi = branch ? fihi : fuhi;
    const unsigned short* flo = branch ? filo : fulo;
    const float* fc_a_b  = branch ? fc_i_b         : fc_u_b;
    const float* fc_r_b  = branch ? fc_ri_b        : fc_ru_b;
    const float* h_w     = branch ? h_i_w          : h_u_w;
    const float* h_b     = branch ? h_i_b          : h_u_b;
    float*       out_vec = branch ? i_vec          : u_vec;

    // arena: [0,8192) Abuf0 | [8192,16384) Abuf1 | [16384,24576) Bbuf0 |
    //        [24576,32768) Bbuf1.  Epilogue overlays review[50][68] on [0,13600).
    __shared__ __align__(16) unsigned char arena[32768];
    __shared__ __align__(16) float lds_att[ND];
    __shared__ float lds_logit[NR + 2];

    const int tid = threadIdx.x, wave = tid >> 6, lane = tid & 63;
    const int g = lane >> 4, c16 = lane & 15;
    const int id = ids[b];

    if (tid < ND) lds_att[tid] = att_w[(size_t)id * ND + tid];

    const float* Abase = r_topic + (size_t)b * NR * NT;

    // ---- staging helpers (per wave: 2 A-instrs + 2 B-instrs = 4 KB in flight)
    auto stageA = [&](int kk, unsigned char* ab) {
#pragma unroll
        for (int i = 0; i < 2; ++i) {
            int s = wave * 2 + i;
            int cid = s * 64 + lane;          // chunk id = LDS offset /16
            int row = cid >> 3;
            int slot = cid & 7;
            int d = (slot - row) & 7;         // = g*2 + h  (XOR-swizzled placement)
            int rc = row < NR ? row : NR - 1; // clamp pad rows
            const float* src = Abase + (size_t)rc * NT + kk * 32 + (d >> 1) * 8 + (d & 1) * 4;
            gload16(src, ab + s * 1024);
        }
    };
    auto stageB = [&](int kk, unsigned char* bbp) {
        const unsigned char* sh = (const unsigned char*)bhi + kk * 4096 + wave * 1024 + (size_t)lane * 16;
        gload16(sh, bbp + wave * 1024);
        const unsigned char* sl = (const unsigned char*)blo + kk * 4096 + wave * 1024 + (size_t)lane * 16;
        gload16(sl, bbp + 4096 + wave * 1024);
    };

    f32x4 acc[4];
#pragma unroll
    for (int n = 0; n < 4; ++n) acc[n] = (f32x4){0.f, 0.f, 0.f, 0.f};

    stageA(0, arena);
    stageB(0, arena + 16384);

    const int rowm = wave * 16 + c16;         // this lane's M row (0..63)
    for (int kk = 0; kk < NKK; ++kk) {
        __syncthreads();                      // buf[kk&1] staged; prev reads done
        if (kk + 1 < NKK) {
            unsigned char* an = ((kk + 1) & 1) ? arena + 8192 : arena;
            unsigned char* bn = ((kk + 1) & 1) ? arena + 24576 : arena + 16384;
            stageA(kk + 1, an);
            stageB(kk + 1, bn);
        }
        const unsigned char* ab = (kk & 1) ? arena + 8192 : arena;
        const unsigned char* bbf = (kk & 1) ? arena + 24576 : arena + 16384;

        float4 a0 = *reinterpret_cast<const float4*>(ab + (rowm * 8 + ((g * 2 + rowm) & 7)) * 16);
        float4 a1 = *reinterpret_cast<const float4*>(ab + (rowm * 8 + ((g * 2 + 1 + rowm) & 7)) * 16);
        bf16x8 ah, al;
        cvt8_fast(a0, a1, ah, al);
#pragma unroll
        for (int n = 0; n < 4; ++n) {
            bf16x8 bh = *reinterpret_cast<const bf16x8*>(bbf + (n * 64 + lane) * 16);
            bf16x8 bl = *reinterpret_cast<const bf16x8*>(bbf + 4096 + (n * 64 + lane) * 16);
            acc[n] = __builtin_amdgcn_mfma_f32_16x16x32_bf16(ah, bh, acc[n], 0, 0, 0);
            acc[n] = __builtin_amdgcn_mfma_f32_16x16x32_bf16(al, bh, acc[n], 0, 0, 0);
            acc[n] = __builtin_amdgcn_mfma_f32_16x16x32_bf16(ah, bl, acc[n], 0, 0, 0);
        }
    }

    __syncthreads();                          // all buf reads done; stray loads landed
    float (*rev)[REVP] = reinterpret_cast<float(*)[REVP]>(arena);
#pragma unroll
    for (int n = 0; n < 4; ++n)
#pragma unroll
        for (int r4 = 0; r4 < 4; ++r4) {
            int r = wave * 16 + g * 4 + r4;
            if (r < NR) rev[r][n * 16 + c16] = acc[n][r4];
        }
    __syncthreads();

    // ---- epilogue s-matmul: s[50x64] = review@fcR + att@fcA (K=128, bf16-split)
    f32x4 s4[4];
#pragma unroll
    for (int n = 0; n < 4; ++n) s4[n] = (f32x4){0.f, 0.f, 0.f, 0.f};

#pragma unroll
    for (int kk2 = 0; kk2 < 4; ++kk2) {
        bf16x8 ah, al;
        if (kk2 < 2) {
            int row = rowm < NR ? rowm : NR - 1;
            const float* rp = &rev[row][kk2 * 32 + g * 8];
            cvt8_fast(*reinterpret_cast<const float4*>(rp),
                      *reinterpret_cast<const float4*>(rp + 4), ah, al);
        } else {
            const float* ap = &lds_att[(kk2 - 2) * 32 + g * 8];
            cvt8_fast(*reinterpret_cast<const float4*>(ap),
                      *reinterpret_cast<const float4*>(ap + 4), ah, al);
        }
#pragma unroll
        for (int n = 0; n < 4; ++n) {
            const size_t off = (size_t)((kk2 * 4 + n) * 64 + lane) * 8;
            bf16x8 bh = *reinterpret_cast<const bf16x8*>(fhi + off);
            bf16x8 bl = *reinterpret_cast<const bf16x8*>(flo + off);
            s4[n] = __builtin_amdgcn_mfma_f32_16x16x32_bf16(ah, bh, s4[n], 0, 0, 0);
            s4[n] = __builtin_amdgcn_mfma_f32_16x16x32_bf16(al, bh, s4[n], 0, 0, 0);
            s4[n] = __builtin_amdgcn_mfma_f32_16x16x32_bf16(ah, bl, s4[n], 0, 0, 0);
        }
    }

    // bias + relu + dot with h_w, then 16-lane reduce -> logits
    const float hb = h_b[0];
    float p0 = 0.f, p1 = 0.f, p2 = 0.f, p3 = 0.f;
#pragma unroll
    for (int n = 0; n < 4; ++n) {
        float hwn = h_w[n * 16 + c16];
        float bs = fc_r_b[n * 16 + c16] + fc_a_b[n * 16 + c16];
        p0 = fmaf(fmaxf(s4[n][0] + bs, 0.f), hwn, p0);
        p1 = fmaf(fmaxf(s4[n][1] + bs, 0.f), hwn, p1);
        p2 = fmaf(fmaxf(s4[n][2] + bs, 0.f), hwn, p2);
        p3 = fmaf(fmaxf(s4[n][3] + bs, 0.f), hwn, p3);
    }
#pragma unroll
    for (int off = 1; off < 16; off <<= 1) {
        p0 += __shfl_xor(p0, off);
        p1 += __shfl_xor(p1, off);
        p2 += __shfl_xor(p2, off);
        p3 += __shfl_xor(p3, off);
    }
    if (c16 == 0) {
        int rb = wave * 16 + g * 4;
        if (rb + 0 < NR) lds_logit[rb + 0] = p0 + hb;
        if (rb + 1 < NR) lds_logit[rb + 1] = p1 + hb;
        if (rb + 2 < NR) lds_logit[rb + 2] = p2 + hb;
        if (rb + 3 < NR) lds_logit[rb + 3] = p3 + hb;
    }
    __syncthreads();

    // softmax + pooling + colsum scale + emb add (wave 0)
    if (wave == 0) {
        float m = -1e30f;
        for (int r = 0; r < NR; ++r) m = fmaxf(m, lds_logit[r]);
        float sum = 0.f;
        for (int r = 0; r < NR; ++r) sum += __expf(lds_logit[r] - m);
        float inv = 1.f / sum;
        float feat = 0.f;
        for (int r = 0; r < NR; ++r)
            feat = fmaf(__expf(lds_logit[r] - m), rev[r][lane], feat);
        feat *= inv;
        out_vec[(size_t)b * ND + lane] = feat * colsum[lane] + emb_w[(size_t)id * ND + lane];
    }
}

// ---------------------------------------------------------------------------
__global__ __launch_bounds__(64) void final_kernel(
    const float* __restrict__ u_vec, const float* __restrict__ i_vec,
    const float* __restrict__ fc_pre_w, const float* __restrict__ fc_pre_b,
    float* __restrict__ out)
{
    int b = blockIdx.x, lane = threadIdx.x;
    float v = u_vec[(size_t)b * ND + lane] * fc_pre_w[lane]
            + i_vec[(size_t)b * ND + lane] * fc_pre_w[ND + lane];
#pragma unroll
    for (int off = 32; off; off >>= 1) v += __shfl_xor(v, off);
    if (lane == 0) out[b] = fmaxf(v + fc_pre_b[0], 0.f);
}

// ---------------------------------------------------------------------------
extern "C" void kernel_launch(void* const* d_in, const int* in_sizes, int n_in,
                              void* d_out, int out_size, void* d_ws, size_t ws_size,
                              hipStream_t stream) {
    (void)in_sizes; (void)n_in; (void)out_size; (void)ws_size;

    const int*   user         = (const int*)d_in[0];
    const int*   item         = (const int*)d_in[1];
    const float* user_r_topic = (const float*)d_in[2];
    const float* item_r_topic = (const float*)d_in[3];
    const float* user_embed_w = (const float*)d_in[4];
    const float* item_embed_w = (const float*)d_in[5];
    const float* user_att_w   = (const float*)d_in[6];
    const float* item_att_w   = (const float*)d_in[7];
    const float* topic_w      = (const float*)d_in[8];
    const float* fc_u_w       = (const float*)d_in[9];
    const float* fc_u_b       = (const float*)d_in[10];
    const float* fc_ru_w      = (const float*)d_in[11];
    const float* fc_ru_b      = (const float*)d_in[12];
    const float* fc_i_w       = (const float*)d_in[13];
    const float* fc_i_b       = (const float*)d_in[14];
    const float* fc_ri_w      = (const float*)d_in[15];
    const float* fc_ri_b      = (const float*)d_in[16];
    const float* h_u_w        = (const float*)d_in[17];
    const float* h_u_b        = (const float*)d_in[18];
    const float* h_i_w        = (const float*)d_in[19];
    const float* h_i_b        = (const float*)d_in[20];
    const float* fc_pre_w     = (const float*)d_in[21];
    const float* fc_pre_b     = (const float*)d_in[22];

    // workspace layout
    unsigned short* bhi  = (unsigned short*)d_ws;      // 32768
    unsigned short* blo  = bhi + 32768;                // 32768
    unsigned short* fuhi = blo + 32768;                // 8192
    unsigned short* fulo = fuhi + 8192;
    unsigned short* fihi = fulo + 8192;
    unsigned short* filo = fihi + 8192;
    float* colsum = (float*)(filo + 8192);             // 64
    float* u_vec  = colsum + 64;                       // NB*ND
    float* i_vec  = u_vec + NB * ND;                   // NB*ND

    prep_kernel<<<192, 256, 0, stream>>>(topic_w, fc_u_w, fc_ru_w, fc_i_w, fc_ri_w,
                                         bhi, blo, fuhi, fulo, fihi, filo);
    colsum_kernel<<<1, 256, 0, stream>>>(topic_w, colsum);

    branch_kernel<<<2 * NB, 256, 0, stream>>>(
        user, item, user_r_topic, item_r_topic,
        user_embed_w, item_embed_w, user_att_w, item_att_w,
        bhi, blo, fuhi, fulo, fihi, filo,
        fc_u_b, fc_ru_b, fc_i_b, fc_ri_b,
        h_u_w, h_u_b, h_i_w, h_i_b,
        colsum, u_vec, i_vec);

    final_kernel<<<NB, 64, 0, stream>>>(u_vec, i_vec, fc_pre_w, fc_pre_b,
                                        (float*)d_out);
}